// Round 5
// baseline (452.778 us; speedup 1.0000x reference)
//
#include <hip/hip_runtime.h>
#include <hip/hip_bf16.h>
#include <stdint.h>

// Problem constants (fixed by the reference)
#define NPTS   1048576
#define HID    256
#define NQ     1024
#define HQ     128
#define HC     128
#define CIN    64
#define CORE_N 262144   // 64*64*64
#define NBLK_CORE 2064  // 129*64/4

// ws layout (floats):
// [0..63]    s0
// [64..127]  s1
// [128..255] t (core_mlp hidden tanh)
// [256..319] c[64] accumulators (atomicAdd; zeroed in k_small blk2)
// [320..1343] table: 256 x float4 (g0,g1,g2, -2w)
// [1344]     b_off (= bx2@c + sum_j w_j)
// [1345]     (uint) completion counter for k_core last-block prep

#define TWO_LOG2E 2.885390081777927f  // 2*log2(e)

// dtype sniff: eq_param == 1.0 exactly. bf16(1.0) = 0x3F80 in u16[0];
// fp32(1.0) = 0x3F800000 -> u16[0] = 0x0000.
__device__ __forceinline__ bool sniff_bf16(const void* eq) {
    return ((const uint16_t*)eq)[0] == 0x3F80u;
}

__device__ __forceinline__ float ldv(const void* p, int i, bool b16) {
    return b16 ? __bfloat162float(((const __hip_bfloat16*)p)[i])
               : ((const float*)p)[i];
}

__device__ __forceinline__ float fast_tanh(float x) {
    float e = __builtin_amdgcn_exp2f(x * TWO_LOG2E);
    float r = __builtin_amdgcn_rcpf(e + 1.0f);
    return fmaf(-2.0f, r, 1.0f);
}

// ---------------- K1: s0, s1, t, zero c + counter ----------------
__global__ __launch_bounds__(1024) void k_small(
    const void* __restrict__ eq_param,
    const void* __restrict__ qx0, const void* __restrict__ qx1,
    const void* __restrict__ Wq01, const void* __restrict__ bq01,
    const void* __restrict__ Wq02, const void* __restrict__ bq02,
    const void* __restrict__ Wq11, const void* __restrict__ bq11,
    const void* __restrict__ Wq12, const void* __restrict__ bq12,
    const void* __restrict__ core_init,
    const void* __restrict__ Wc1, const void* __restrict__ bc1,
    float* __restrict__ ws)
{
    bool b16 = sniff_bf16(eq_param);
    int tid = threadIdx.x;
    int blk = blockIdx.x;
    if (blk == 2) {
        // t[j] = tanh(core_init @ Wc1 + bc1); zero c accumulators + counter
        if (tid < HC) {
            float acc = ldv(bc1, tid, b16);
            for (int i = 0; i < CIN; ++i)
                acc = fmaf(ldv(core_init, i, b16), ldv(Wc1, i * HC + tid, b16), acc);
            ws[128 + tid] = fast_tanh(acc);
        } else if (tid < HC + 64) {
            ws[256 + (tid - HC)] = 0.0f;
        } else if (tid == HC + 64) {
            ((unsigned*)ws)[1345] = 0u;
        }
        return;
    }
    const void* qx = blk ? qx1 : qx0;
    const void* W1 = blk ? Wq11 : Wq01;
    const void* b1 = blk ? bq11 : bq01;
    const void* W2 = blk ? Wq12 : Wq02;
    const void* b2 = blk ? bq12 : bq02;

    __shared__ float upart[8][HQ];
    __shared__ float ypart[8];
    __shared__ float uj[HQ];
    __shared__ float Ytot;

    int j = tid & 127;       // hidden unit
    int cs = tid >> 7;       // quad-slice 0..7
    float w1 = ldv(W1, j, b16), b1j = ldv(b1, j, b16);
    float eq = ldv(eq_param, 0, b16);
    const float PI = 3.14159265358979323846f;

    float u = 0.f, ysum = 0.f;
    for (int c = cs * 128; c < cs * 128 + 128; ++c) {
        float q = ldv(qx, c, b16);
        float y = __sinf(PI * eq * q);
        ysum += y;
        u += y * fast_tanh(fmaf(q, w1, b1j));
    }
    upart[cs][j] = u;
    if (j == 0) ypart[cs] = ysum;
    __syncthreads();
    if (tid < HQ) {
        float s = 0.f;
        for (int k = 0; k < 8; ++k) s += upart[k][tid];
        uj[tid] = s;
        if (tid == 0) { float Y = 0.f; for (int k = 0; k < 8; ++k) Y += ypart[k]; Ytot = Y; }
    }
    __syncthreads();
    if (tid < 64) {
        float s = Ytot * ldv(b2, tid, b16);
        for (int jj = 0; jj < HQ; ++jj) s = fmaf(uj[jj], ldv(W2, jj * 64 + tid, b16), s);
        ws[blk * 64 + tid] = s;
    }
}

// ---------------- K2 row dot helpers ----------------
// c[a] = sum_{j,xy} t[j]*Wc2[j, a*4096+xy]*s0[x]*s1[y] (+bias row)
__device__ __forceinline__ float core_row_bf16(
    const __hip_bfloat16* __restrict__ row, const float* __restrict__ ws, int lane)
{
    // element e of lane's 16B chunk at iter k: xy = k*512 + lane*8 + e
    // -> x = k*8 + (lane>>3), y = (lane&7)*8 + e
    int g = lane >> 3, yb = (lane & 7) * 8;
    float s1v[8], s0v[8];
    #pragma unroll
    for (int e = 0; e < 8; ++e) s1v[e] = ws[64 + yb + e];
    #pragma unroll
    for (int k = 0; k < 8; ++k) s0v[k] = ws[k * 8 + g];

    const uint4* rp = (const uint4*)row;
    float acc = 0.f;
    #pragma unroll
    for (int k = 0; k < 8; ++k) {
        uint4 v = rp[k * 64 + lane];
        uint32_t uu[4] = {v.x, v.y, v.z, v.w};
        float inner = 0.f;
        #pragma unroll
        for (int q = 0; q < 4; ++q) {
            float lo = __uint_as_float(uu[q] << 16);
            float hi = __uint_as_float(uu[q] & 0xffff0000u);
            inner = fmaf(lo, s1v[2 * q], inner);
            inner = fmaf(hi, s1v[2 * q + 1], inner);
        }
        acc = fmaf(inner, s0v[k], acc);
    }
    return acc;
}

__device__ __forceinline__ float core_row_f32(
    const float* __restrict__ row, const float* __restrict__ ws, int lane)
{
    // element e of lane's 16B chunk at iter k: xy = k*256 + lane*4 + e
    // -> x = k*4 + (lane>>4), y = (lane&15)*4 + e
    int g = lane >> 4, yb = (lane & 15) * 4;
    float s1v[4], s0v[16];
    #pragma unroll
    for (int e = 0; e < 4; ++e) s1v[e] = ws[64 + yb + e];
    #pragma unroll
    for (int k = 0; k < 16; ++k) s0v[k] = ws[k * 4 + g];

    const float4* rp = (const float4*)row;
    float acc = 0.f;
    #pragma unroll
    for (int k = 0; k < 16; ++k) {
        float4 v = rp[k * 64 + lane];
        float inner = v.x * s1v[0];
        inner = fmaf(v.y, s1v[1], inner);
        inner = fmaf(v.z, s1v[2], inner);
        inner = fmaf(v.w, s1v[3], inner);
        acc = fmaf(inner, s0v[k], acc);
    }
    return acc;
}

// K2: core contraction; the LAST block to finish also builds the k_main table.
__global__ __launch_bounds__(256) void k_core(
    const void* __restrict__ Wc2, const void* __restrict__ bc2,
    const void* __restrict__ eq_param,
    const void* __restrict__ Wx1, const void* __restrict__ bx1,
    const void* __restrict__ Wx2, const void* __restrict__ bx2,
    float* __restrict__ ws, float* __restrict__ cacc)
{
    bool b16 = sniff_bf16(eq_param);
    int tid = threadIdx.x;
    int wave = tid >> 6, lane = tid & 63;
    int gid = blockIdx.x * 4 + wave;   // 0..8255
    int j = gid >> 6;                  // 0..128 (128 == bias row)
    int a = gid & 63;

    const void* base = (j < HC) ? Wc2 : bc2;
    size_t off = (j < HC) ? ((size_t)j * CORE_N + (size_t)a * 4096)
                          : ((size_t)a * 4096);
    float coeff = (j < HC) ? ws[128 + j] : 1.0f;

    float acc = b16 ? core_row_bf16((const __hip_bfloat16*)base + off, ws, lane)
                    : core_row_f32((const float*)base + off, ws, lane);

    for (int offl = 32; offl > 0; offl >>= 1) acc += __shfl_down(acc, offl);
    if (lane == 0) atomicAdd(&cacc[a], acc * coeff);

    // ---- last-block-done prep (replaces the old k_prep kernel) ----
    __shared__ int is_last;
    __shared__ float cv[64];
    __shared__ float red[4];
    __syncthreads();                    // drains this block's atomics (vmcnt)
    if (tid == 0) {
        __threadfence();
        unsigned v = atomicAdd((unsigned*)ws + 1345, 1u);
        is_last = (v == NBLK_CORE - 1u);
    }
    __syncthreads();
    if (!is_last) return;

    __threadfence();
    if (tid < 64) cv[tid] = atomicAdd(&cacc[tid], 0.0f);  // coherent read of c
    __syncthreads();

    float w = 0.f;
    for (int aa = 0; aa < 64; ++aa) w = fmaf(ldv(Wx2, tid * 64 + aa, b16), cv[aa], w);
    float4 t;
    t.x = TWO_LOG2E * ldv(Wx1, tid, b16);         // Wx1[0, j]
    t.y = TWO_LOG2E * ldv(Wx1, HID + tid, b16);   // Wx1[1, j]
    t.z = TWO_LOG2E * ldv(bx1, tid, b16);
    t.w = -2.0f * w;                               // tanh = 1 - 2r; +w folded into b_off
    ((float4*)(ws + 320))[tid] = t;

    // b_off' = bx2@c + sum_j w_j
    float p = w + ((tid < 64) ? ldv(bx2, tid, b16) * cv[tid] : 0.f);
    for (int offl = 32; offl > 0; offl >>= 1) p += __shfl_down(p, offl);
    if ((tid & 63) == 0) red[tid >> 6] = p;
    __syncthreads();
    if (tid == 0) ws[1344] = red[0] + red[1] + red[2] + red[3];
}

// ---------------- K3: out[n] = b_off' + sum_j (-2 w_j) * rcp(exp2(g)+1) ----------------
// 2048 blocks x 256 threads x 2 pts/thread. Paired reciprocal: one v_rcp
// serves both points (1/A = B*rcp(AB)), cutting trans ops 2.0 -> 1.5 per elem.
// min(g,30) clamp keeps the pair finite (tanh(10.4) == 1.0f exactly in fp32).
__global__ __launch_bounds__(256) void k_main(
    const void* __restrict__ x, const void* __restrict__ eq_param,
    const float* __restrict__ ws, void* __restrict__ out)
{
    bool b16 = sniff_bf16(eq_param);
    const float4* __restrict__ tbl = (const float4*)(ws + 320);
    const int stride = NPTS / 2;   // 524288
    int p0 = blockIdx.x * 256 + threadIdx.x;

    float x0[2], x1[2], acc[2];
    if (b16) {
        #pragma unroll
        for (int i = 0; i < 2; ++i) {
            uint32_t u = ((const uint32_t*)x)[p0 + i * stride];  // packs x[p,0], x[p,1]
            x0[i] = __uint_as_float(u << 16);
            x1[i] = __uint_as_float(u & 0xffff0000u);
        }
    } else {
        #pragma unroll
        for (int i = 0; i < 2; ++i) {
            float2 v = ((const float2*)x)[p0 + i * stride];
            x0[i] = v.x;
            x1[i] = v.y;
        }
    }
    float boff = ws[1344];
    acc[0] = boff; acc[1] = boff;

    #pragma unroll 4
    for (int jj = 0; jj < HID; ++jj) {
        float4 t = tbl[jj];
        float g0 = fmaf(x0[0], t.x, fmaf(x1[0], t.y, t.z));
        float g1 = fmaf(x0[1], t.x, fmaf(x1[1], t.y, t.z));
        g0 = __builtin_fminf(g0, 30.0f);
        g1 = __builtin_fminf(g1, 30.0f);
        float A = __builtin_amdgcn_exp2f(g0) + 1.0f;
        float B = __builtin_amdgcn_exp2f(g1) + 1.0f;
        float rP = __builtin_amdgcn_rcpf(A * B);
        acc[0] = fmaf(t.w, B * rP, acc[0]);   // t.w * (1/A)
        acc[1] = fmaf(t.w, A * rP, acc[1]);   // t.w * (1/B)
    }
    if (b16) {
        #pragma unroll
        for (int i = 0; i < 2; ++i)
            ((__hip_bfloat16*)out)[p0 + i * stride] = __float2bfloat16(acc[i]);
    } else {
        #pragma unroll
        for (int i = 0; i < 2; ++i)
            ((float*)out)[p0 + i * stride] = acc[i];
    }
}

extern "C" void kernel_launch(void* const* d_in, const int* in_sizes, int n_in,
                              void* d_out, int out_size, void* d_ws, size_t ws_size,
                              hipStream_t stream) {
    (void)in_sizes; (void)n_in; (void)out_size; (void)ws_size;
    const void* input     = d_in[0];
    const void* eq_param  = d_in[1];
    const void* quad_x0   = d_in[2];
    const void* quad_x1   = d_in[3];
    const void* core_init = d_in[4];
    const void* Wx1  = d_in[5];
    const void* bx1  = d_in[6];
    const void* Wx2  = d_in[7];
    const void* bx2  = d_in[8];
    const void* Wq01 = d_in[9];
    const void* bq01 = d_in[10];
    const void* Wq02 = d_in[11];
    const void* bq02 = d_in[12];
    const void* Wq11 = d_in[13];
    const void* bq11 = d_in[14];
    const void* Wq12 = d_in[15];
    const void* bq12 = d_in[16];
    const void* Wc1  = d_in[17];
    const void* bc1  = d_in[18];
    const void* Wc2  = d_in[19];
    const void* bc2  = d_in[20];

    float* ws = (float*)d_ws;

    // K1: quadrature sums s0,s1 + core hidden t + zero c accumulators/counter
    k_small<<<3, 1024, 0, stream>>>(eq_param, quad_x0, quad_x1,
                                    Wq01, bq01, Wq02, bq02,
                                    Wq11, bq11, Wq12, bq12,
                                    core_init, Wc1, bc1, ws);
    // K2: Tucker-core contraction -> c[64]; last block builds the k_main table
    k_core<<<NBLK_CORE, 256, 0, stream>>>(Wc2, bc2, eq_param,
                                          Wx1, bx1, Wx2, bx2, ws, ws + 256);
    // K3: the big fused pointwise MLP + dot (2 pts/thread, paired rcp)
    k_main<<<NPTS / 512, 256, 0, stream>>>(input, eq_param, ws, d_out);
}

// Round 6
// 352.374 us; speedup vs baseline: 1.2849x; 1.2849x over previous
//
#include <hip/hip_runtime.h>
#include <hip/hip_bf16.h>
#include <stdint.h>

// Problem constants (fixed by the reference)
#define NPTS   1048576
#define HID    256
#define NQ     1024
#define HQ     128
#define HC     128
#define CIN    64
#define CORE_N 262144   // 64*64*64

// ws layout (floats):
// [0..63]      s0
// [64..127]    s1
// [128..255]   t (core_mlp hidden tanh)
// [256+a*32]   c[a] accumulators, a=0..63 (atomicAdd; one 128B line each; zeroed in k_small)
// [2560..3583] table: 256 x float4 (g0,g1,g2, -2w)
// [3584]       b_off (= bx2@c + sum_j w_j)

#define TWO_LOG2E 2.885390081777927f  // 2*log2(e)

// dtype sniff: eq_param == 1.0 exactly. bf16(1.0) = 0x3F80 in u16[0];
// fp32(1.0) = 0x3F800000 -> u16[0] = 0x0000.
__device__ __forceinline__ bool sniff_bf16(const void* eq) {
    return ((const uint16_t*)eq)[0] == 0x3F80u;
}

__device__ __forceinline__ float ldv(const void* p, int i, bool b16) {
    return b16 ? __bfloat162float(((const __hip_bfloat16*)p)[i])
               : ((const float*)p)[i];
}

__device__ __forceinline__ float fast_tanh(float x) {
    float e = __builtin_amdgcn_exp2f(x * TWO_LOG2E);
    float r = __builtin_amdgcn_rcpf(e + 1.0f);
    return fmaf(-2.0f, r, 1.0f);
}

// ---------------- K1: s0, s1, t, zero c ----------------
__global__ __launch_bounds__(1024) void k_small(
    const void* __restrict__ eq_param,
    const void* __restrict__ qx0, const void* __restrict__ qx1,
    const void* __restrict__ Wq01, const void* __restrict__ bq01,
    const void* __restrict__ Wq02, const void* __restrict__ bq02,
    const void* __restrict__ Wq11, const void* __restrict__ bq11,
    const void* __restrict__ Wq12, const void* __restrict__ bq12,
    const void* __restrict__ core_init,
    const void* __restrict__ Wc1, const void* __restrict__ bc1,
    float* __restrict__ ws)
{
    bool b16 = sniff_bf16(eq_param);
    int tid = threadIdx.x;
    int blk = blockIdx.x;
    if (blk == 2) {
        // t[j] = tanh(core_init @ Wc1 + bc1); zero spread c accumulators
        if (tid < HC) {
            float acc = ldv(bc1, tid, b16);
            for (int i = 0; i < CIN; ++i)
                acc = fmaf(ldv(core_init, i, b16), ldv(Wc1, i * HC + tid, b16), acc);
            ws[128 + tid] = fast_tanh(acc);
        } else if (tid < HC + 64) {
            ws[256 + (tid - HC) * 32] = 0.0f;
        }
        return;
    }
    const void* qx = blk ? qx1 : qx0;
    const void* W1 = blk ? Wq11 : Wq01;
    const void* b1 = blk ? bq11 : bq01;
    const void* W2 = blk ? Wq12 : Wq02;
    const void* b2 = blk ? bq12 : bq02;

    __shared__ float upart[8][HQ];
    __shared__ float ypart[8];
    __shared__ float uj[HQ];
    __shared__ float Ytot;

    int j = tid & 127;       // hidden unit
    int cs = tid >> 7;       // quad-slice 0..7
    float w1 = ldv(W1, j, b16), b1j = ldv(b1, j, b16);
    float eq = ldv(eq_param, 0, b16);
    const float PI = 3.14159265358979323846f;

    float u = 0.f, ysum = 0.f;
    for (int c = cs * 128; c < cs * 128 + 128; ++c) {
        float q = ldv(qx, c, b16);
        float y = __sinf(PI * eq * q);
        ysum += y;
        u += y * fast_tanh(fmaf(q, w1, b1j));
    }
    upart[cs][j] = u;
    if (j == 0) ypart[cs] = ysum;
    __syncthreads();
    if (tid < HQ) {
        float s = 0.f;
        for (int k = 0; k < 8; ++k) s += upart[k][tid];
        uj[tid] = s;
        if (tid == 0) { float Y = 0.f; for (int k = 0; k < 8; ++k) Y += ypart[k]; Ytot = Y; }
    }
    __syncthreads();
    if (tid < 64) {
        float s = Ytot * ldv(b2, tid, b16);
        for (int jj = 0; jj < HQ; ++jj) s = fmaf(uj[jj], ldv(W2, jj * 64 + tid, b16), s);
        ws[blk * 64 + tid] = s;
    }
}

// ---------------- K2 chunk-dot helpers ----------------
// One chunk = one (j,a) row segment of 4096 elements: sum_xy row[xy]*s0[x]*s1[y]
__device__ __forceinline__ float chunk_dot_bf16(
    const uint4* __restrict__ rp, int lane,
    const float* __restrict__ s0v, const float* __restrict__ s1v)
{
    float acc = 0.f;
    #pragma unroll
    for (int kk = 0; kk < 8; ++kk) {
        uint4 v = rp[kk * 64 + lane];
        uint32_t uu[4] = {v.x, v.y, v.z, v.w};
        float inner = 0.f;
        #pragma unroll
        for (int q = 0; q < 4; ++q) {
            float lo = __uint_as_float(uu[q] << 16);
            float hi = __uint_as_float(uu[q] & 0xffff0000u);
            inner = fmaf(lo, s1v[2 * q], inner);
            inner = fmaf(hi, s1v[2 * q + 1], inner);
        }
        acc = fmaf(inner, s0v[kk], acc);
    }
    return acc;
}

__device__ __forceinline__ float chunk_dot_f32(
    const float4* __restrict__ rp, int lane,
    const float* __restrict__ s0v, const float* __restrict__ s1v)
{
    float acc = 0.f;
    #pragma unroll
    for (int kk = 0; kk < 16; ++kk) {
        float4 v = rp[kk * 64 + lane];
        float inner = v.x * s1v[0];
        inner = fmaf(v.y, s1v[1], inner);
        inner = fmaf(v.z, s1v[2], inner);
        inner = fmaf(v.w, s1v[3], inner);
        acc = fmaf(inner, s0v[kk], acc);
    }
    return acc;
}

// K2: streaming core contraction. 512 blocks x 4 waves = 2048 waves.
// Wave W: a = W&63 fixed, loops j = (W>>6) + 32*k, k=0..3 (32KB streamed/wave).
// Waves W<64 also handle the bias row chunk for a=W.
__global__ __launch_bounds__(256) void k_core(
    const void* __restrict__ Wc2, const void* __restrict__ bc2,
    const void* __restrict__ eq_param,
    const float* __restrict__ ws, float* __restrict__ cacc)
{
    bool b16 = sniff_bf16(eq_param);
    int tid = threadIdx.x;
    int lane = tid & 63;
    int W = blockIdx.x * 4 + (tid >> 6);   // 0..2047
    int a = W & 63;
    int j0 = W >> 6;                        // 0..31

    float acc = 0.f;
    if (b16) {
        int g = lane >> 3, yb = (lane & 7) * 8;
        float s1v[8], s0v[8];
        #pragma unroll
        for (int e = 0; e < 8; ++e) s1v[e] = ws[64 + yb + e];
        #pragma unroll
        for (int kk = 0; kk < 8; ++kk) s0v[kk] = ws[kk * 8 + g];

        const uint4* base = (const uint4*)((const __hip_bfloat16*)Wc2 + (size_t)a * 4096);
        const size_t rowstep = CORE_N / 8;   // uint4 per j-row
        #pragma unroll 2
        for (int k = 0; k < 4; ++k) {
            int j = j0 + 32 * k;
            float d = chunk_dot_bf16(base + (size_t)j * rowstep, lane, s0v, s1v);
            acc = fmaf(d, ws[128 + j], acc);
        }
        if (W < 64)
            acc += chunk_dot_bf16((const uint4*)((const __hip_bfloat16*)bc2 + (size_t)a * 4096),
                                  lane, s0v, s1v);
    } else {
        int g = lane >> 4, yb = (lane & 15) * 4;
        float s1v[4], s0v[16];
        #pragma unroll
        for (int e = 0; e < 4; ++e) s1v[e] = ws[64 + yb + e];
        #pragma unroll
        for (int kk = 0; kk < 16; ++kk) s0v[kk] = ws[kk * 4 + g];

        const float4* base = (const float4*)((const float*)Wc2 + (size_t)a * 4096);
        const size_t rowstep = CORE_N / 4;   // float4 per j-row
        for (int k = 0; k < 4; ++k) {
            int j = j0 + 32 * k;
            float d = chunk_dot_f32(base + (size_t)j * rowstep, lane, s0v, s1v);
            acc = fmaf(d, ws[128 + j], acc);
        }
        if (W < 64)
            acc += chunk_dot_f32((const float4*)((const float*)bc2 + (size_t)a * 4096),
                                 lane, s0v, s1v);
    }

    for (int offl = 32; offl > 0; offl >>= 1) acc += __shfl_down(acc, offl);
    if (lane == 0) atomicAdd(&cacc[a * 32], acc);
}

// ---------------- K2b: build fused table (g0,g1,g2,-2w) + b_off' ----------------
__global__ __launch_bounds__(256) void k_prep(
    const void* __restrict__ Wx1, const void* __restrict__ bx1,
    const void* __restrict__ Wx2, const void* __restrict__ bx2,
    const void* __restrict__ eq_param,
    const float* __restrict__ cacc, float* __restrict__ ws)
{
    bool b16 = sniff_bf16(eq_param);
    __shared__ float cv[64];
    __shared__ float red[4];
    int tid = threadIdx.x;
    if (tid < 64) cv[tid] = cacc[tid * 32];
    __syncthreads();
    float w = 0.f;
    for (int a = 0; a < 64; ++a) w = fmaf(ldv(Wx2, tid * 64 + a, b16), cv[a], w);
    float4 t;
    t.x = TWO_LOG2E * ldv(Wx1, tid, b16);         // Wx1[0, j]
    t.y = TWO_LOG2E * ldv(Wx1, HID + tid, b16);   // Wx1[1, j]
    t.z = TWO_LOG2E * ldv(bx1, tid, b16);
    t.w = -2.0f * w;                               // tanh = 1 - 2r; +w folded into b_off
    ((float4*)(ws + 2560))[tid] = t;

    // b_off' = bx2@c + sum_j w_j
    float p = w + ((tid < 64) ? ldv(bx2, tid, b16) * cv[tid] : 0.f);
    for (int offl = 32; offl > 0; offl >>= 1) p += __shfl_down(p, offl);
    if ((tid & 63) == 0) red[tid >> 6] = p;
    __syncthreads();
    if (tid == 0) ws[3584] = red[0] + red[1] + red[2] + red[3];
}

// ---------------- K3: out[n] = b_off' + sum_j (-2 w_j) * rcp(exp2(g)+1) ----------------
// 2048 blocks x 256 threads x 2 pts/thread. Paired reciprocal: one v_rcp
// serves both points (1/A = B*rcp(AB)), cutting trans ops 2.0 -> 1.5 per elem.
// min(g,30) clamp keeps the pair finite (tanh at g=30 is 1.0f to fp32).
__global__ __launch_bounds__(256) void k_main(
    const void* __restrict__ x, const void* __restrict__ eq_param,
    const float* __restrict__ ws, void* __restrict__ out)
{
    bool b16 = sniff_bf16(eq_param);
    const float4* __restrict__ tbl = (const float4*)(ws + 2560);
    const int stride = NPTS / 2;   // 524288
    int p0 = blockIdx.x * 256 + threadIdx.x;

    float x0[2], x1[2], acc[2];
    if (b16) {
        #pragma unroll
        for (int i = 0; i < 2; ++i) {
            uint32_t u = ((const uint32_t*)x)[p0 + i * stride];  // packs x[p,0], x[p,1]
            x0[i] = __uint_as_float(u << 16);
            x1[i] = __uint_as_float(u & 0xffff0000u);
        }
    } else {
        #pragma unroll
        for (int i = 0; i < 2; ++i) {
            float2 v = ((const float2*)x)[p0 + i * stride];
            x0[i] = v.x;
            x1[i] = v.y;
        }
    }
    float boff = ws[3584];
    acc[0] = boff; acc[1] = boff;

    #pragma unroll 4
    for (int jj = 0; jj < HID; ++jj) {
        float4 t = tbl[jj];
        float g0 = fmaf(x0[0], t.x, fmaf(x1[0], t.y, t.z));
        float g1 = fmaf(x0[1], t.x, fmaf(x1[1], t.y, t.z));
        g0 = __builtin_fminf(g0, 30.0f);
        g1 = __builtin_fminf(g1, 30.0f);
        float A = __builtin_amdgcn_exp2f(g0) + 1.0f;
        float B = __builtin_amdgcn_exp2f(g1) + 1.0f;
        float rP = __builtin_amdgcn_rcpf(A * B);
        acc[0] = fmaf(t.w, B * rP, acc[0]);   // t.w * (1/A)
        acc[1] = fmaf(t.w, A * rP, acc[1]);   // t.w * (1/B)
    }
    if (b16) {
        #pragma unroll
        for (int i = 0; i < 2; ++i)
            ((__hip_bfloat16*)out)[p0 + i * stride] = __float2bfloat16(acc[i]);
    } else {
        #pragma unroll
        for (int i = 0; i < 2; ++i)
            ((float*)out)[p0 + i * stride] = acc[i];
    }
}

extern "C" void kernel_launch(void* const* d_in, const int* in_sizes, int n_in,
                              void* d_out, int out_size, void* d_ws, size_t ws_size,
                              hipStream_t stream) {
    (void)in_sizes; (void)n_in; (void)out_size; (void)ws_size;
    const void* input     = d_in[0];
    const void* eq_param  = d_in[1];
    const void* quad_x0   = d_in[2];
    const void* quad_x1   = d_in[3];
    const void* core_init = d_in[4];
    const void* Wx1  = d_in[5];
    const void* bx1  = d_in[6];
    const void* Wx2  = d_in[7];
    const void* bx2  = d_in[8];
    const void* Wq01 = d_in[9];
    const void* bq01 = d_in[10];
    const void* Wq02 = d_in[11];
    const void* bq02 = d_in[12];
    const void* Wq11 = d_in[13];
    const void* bq11 = d_in[14];
    const void* Wq12 = d_in[15];
    const void* bq12 = d_in[16];
    const void* Wc1  = d_in[17];
    const void* bc1  = d_in[18];
    const void* Wc2  = d_in[19];
    const void* bc2  = d_in[20];

    float* ws = (float*)d_ws;

    // K1: quadrature sums s0,s1 + core hidden t + zero c accumulators
    k_small<<<3, 1024, 0, stream>>>(eq_param, quad_x0, quad_x1,
                                    Wq01, bq01, Wq02, bq02,
                                    Wq11, bq11, Wq12, bq12,
                                    core_init, Wc1, bc1, ws);
    // K2: streaming Tucker-core contraction -> c[64] (2048 waves, 4 chunks each)
    k_core<<<512, 256, 0, stream>>>(Wc2, bc2, eq_param, ws, ws + 256);
    // K2b: fold c into per-hidden-unit table + b_off
    k_prep<<<1, 256, 0, stream>>>(Wx1, bx1, Wx2, bx2, eq_param, ws + 256, ws);
    // K3: the big fused pointwise MLP + dot (2 pts/thread, paired rcp)
    k_main<<<NPTS / 512, 256, 0, stream>>>(input, eq_param, ws, d_out);
}

// Round 7
// 339.476 us; speedup vs baseline: 1.3338x; 1.0380x over previous
//
#include <hip/hip_runtime.h>
#include <hip/hip_bf16.h>
#include <stdint.h>

// Problem constants (fixed by the reference)
#define NPTS   1048576
#define HID    256
#define NQ     1024
#define HQ     128
#define HC     128
#define CIN    64
#define CORE_N 262144   // 64*64*64

// ws layout (floats):
// [0..63]      s0
// [64..127]    s1
// [128..255]   t (core_mlp hidden tanh)
// [256+a*32]   c[a] accumulators, a=0..63 (atomicAdd; one 128B line each; zeroed in k_small)
// [2560..3583] table: 256 x float4 (g0,g1,g2, -2w)
// [3584]       b_off (= bx2@c + sum_j w_j)

#define TWO_LOG2E 2.885390081777927f  // 2*log2(e)

typedef float    v2f  __attribute__((ext_vector_type(2)));
typedef uint32_t u32x4 __attribute__((ext_vector_type(4)));
typedef float    f32x4 __attribute__((ext_vector_type(4)));

// dtype sniff: eq_param == 1.0 exactly. bf16(1.0) = 0x3F80 in u16[0];
// fp32(1.0) = 0x3F800000 -> u16[0] = 0x0000.
__device__ __forceinline__ bool sniff_bf16(const void* eq) {
    return ((const uint16_t*)eq)[0] == 0x3F80u;
}

__device__ __forceinline__ float ldv(const void* p, int i, bool b16) {
    return b16 ? __bfloat162float(((const __hip_bfloat16*)p)[i])
               : ((const float*)p)[i];
}

__device__ __forceinline__ float fast_tanh(float x) {
    float e = __builtin_amdgcn_exp2f(x * TWO_LOG2E);
    float r = __builtin_amdgcn_rcpf(e + 1.0f);
    return fmaf(-2.0f, r, 1.0f);
}

// ---------------- K1: s0, s1, t, zero c ----------------
__global__ __launch_bounds__(1024) void k_small(
    const void* __restrict__ eq_param,
    const void* __restrict__ qx0, const void* __restrict__ qx1,
    const void* __restrict__ Wq01, const void* __restrict__ bq01,
    const void* __restrict__ Wq02, const void* __restrict__ bq02,
    const void* __restrict__ Wq11, const void* __restrict__ bq11,
    const void* __restrict__ Wq12, const void* __restrict__ bq12,
    const void* __restrict__ core_init,
    const void* __restrict__ Wc1, const void* __restrict__ bc1,
    float* __restrict__ ws)
{
    bool b16 = sniff_bf16(eq_param);
    int tid = threadIdx.x;
    int blk = blockIdx.x;
    if (blk == 2) {
        // t[j] = tanh(core_init @ Wc1 + bc1); zero spread c accumulators
        if (tid < HC) {
            float acc = ldv(bc1, tid, b16);
            for (int i = 0; i < CIN; ++i)
                acc = fmaf(ldv(core_init, i, b16), ldv(Wc1, i * HC + tid, b16), acc);
            ws[128 + tid] = fast_tanh(acc);
        } else if (tid < HC + 64) {
            ws[256 + (tid - HC) * 32] = 0.0f;
        }
        return;
    }
    const void* qx = blk ? qx1 : qx0;
    const void* W1 = blk ? Wq11 : Wq01;
    const void* b1 = blk ? bq11 : bq01;
    const void* W2 = blk ? Wq12 : Wq02;
    const void* b2 = blk ? bq12 : bq02;

    __shared__ float upart[8][HQ];
    __shared__ float ypart[8];
    __shared__ float uj[HQ];
    __shared__ float Ytot;

    int j = tid & 127;       // hidden unit
    int cs = tid >> 7;       // quad-slice 0..7
    float w1 = ldv(W1, j, b16), b1j = ldv(b1, j, b16);
    float eq = ldv(eq_param, 0, b16);
    const float PI = 3.14159265358979323846f;

    float u = 0.f, ysum = 0.f;
    for (int c = cs * 128; c < cs * 128 + 128; ++c) {
        float q = ldv(qx, c, b16);
        float y = __sinf(PI * eq * q);
        ysum += y;
        u += y * fast_tanh(fmaf(q, w1, b1j));
    }
    upart[cs][j] = u;
    if (j == 0) ypart[cs] = ysum;
    __syncthreads();
    if (tid < HQ) {
        float s = 0.f;
        for (int k = 0; k < 8; ++k) s += upart[k][tid];
        uj[tid] = s;
        if (tid == 0) { float Y = 0.f; for (int k = 0; k < 8; ++k) Y += ypart[k]; Ytot = Y; }
    }
    __syncthreads();
    if (tid < 64) {
        float s = Ytot * ldv(b2, tid, b16);
        for (int jj = 0; jj < HQ; ++jj) s = fmaf(uj[jj], ldv(W2, jj * 64 + tid, b16), s);
        ws[blk * 64 + tid] = s;
    }
}

// ---------------- K2 chunk-dot helpers ----------------
// One chunk = one (j,a) row segment of 4096 elements: sum_xy row[xy]*s0[x]*s1[y]
__device__ __forceinline__ float chunk_dot_bf16(
    const u32x4* __restrict__ rp, int lane,
    const float* __restrict__ s0v, const float* __restrict__ s1v)
{
    float acc = 0.f;
    #pragma unroll
    for (int kk = 0; kk < 8; ++kk) {
        u32x4 v = __builtin_nontemporal_load(rp + kk * 64 + lane);
        float inner = 0.f;
        #pragma unroll
        for (int q = 0; q < 4; ++q) {
            float lo = __uint_as_float(v[q] << 16);
            float hi = __uint_as_float(v[q] & 0xffff0000u);
            inner = fmaf(lo, s1v[2 * q], inner);
            inner = fmaf(hi, s1v[2 * q + 1], inner);
        }
        acc = fmaf(inner, s0v[kk], acc);
    }
    return acc;
}

__device__ __forceinline__ float chunk_dot_f32(
    const f32x4* __restrict__ rp, int lane,
    const float* __restrict__ s0v, const float* __restrict__ s1v)
{
    float acc = 0.f;
    #pragma unroll
    for (int kk = 0; kk < 16; ++kk) {
        f32x4 v = __builtin_nontemporal_load(rp + kk * 64 + lane);
        float inner = v[0] * s1v[0];
        inner = fmaf(v[1], s1v[1], inner);
        inner = fmaf(v[2], s1v[2], inner);
        inner = fmaf(v[3], s1v[3], inner);
        acc = fmaf(inner, s0v[kk], acc);
    }
    return acc;
}

// K2: streaming core contraction. 1024 blocks x 4 waves = 4096 waves (16/CU).
// Wave W: a = W&63 fixed, j = (W>>6) + {0,64} (16KB streamed/wave, fully unrolled).
// Waves W<64 also handle the bias row chunk for a=W.
__global__ __launch_bounds__(256) void k_core(
    const void* __restrict__ Wc2, const void* __restrict__ bc2,
    const void* __restrict__ eq_param,
    const float* __restrict__ ws, float* __restrict__ cacc)
{
    bool b16 = sniff_bf16(eq_param);
    int tid = threadIdx.x;
    int lane = tid & 63;
    int W = blockIdx.x * 4 + (tid >> 6);   // 0..4095
    int a = W & 63;
    int j0 = W >> 6;                        // 0..63

    float acc = 0.f;
    if (b16) {
        int g = lane >> 3, yb = (lane & 7) * 8;
        float s1v[8], s0v[8];
        #pragma unroll
        for (int e = 0; e < 8; ++e) s1v[e] = ws[64 + yb + e];
        #pragma unroll
        for (int kk = 0; kk < 8; ++kk) s0v[kk] = ws[kk * 8 + g];

        const u32x4* base = (const u32x4*)((const __hip_bfloat16*)Wc2 + (size_t)a * 4096);
        const size_t rowstep = CORE_N / 8;   // u32x4 per j-row
        #pragma unroll
        for (int k = 0; k < 2; ++k) {
            int j = j0 + 64 * k;
            float d = chunk_dot_bf16(base + (size_t)j * rowstep, lane, s0v, s1v);
            acc = fmaf(d, ws[128 + j], acc);
        }
        if (W < 64)
            acc += chunk_dot_bf16((const u32x4*)((const __hip_bfloat16*)bc2 + (size_t)a * 4096),
                                  lane, s0v, s1v);
    } else {
        int g = lane >> 4, yb = (lane & 15) * 4;
        float s1v[4], s0v[16];
        #pragma unroll
        for (int e = 0; e < 4; ++e) s1v[e] = ws[64 + yb + e];
        #pragma unroll
        for (int kk = 0; kk < 16; ++kk) s0v[kk] = ws[kk * 4 + g];

        const f32x4* base = (const f32x4*)((const float*)Wc2 + (size_t)a * 4096);
        const size_t rowstep = CORE_N / 4;   // f32x4 per j-row
        #pragma unroll
        for (int k = 0; k < 2; ++k) {
            int j = j0 + 64 * k;
            float d = chunk_dot_f32(base + (size_t)j * rowstep, lane, s0v, s1v);
            acc = fmaf(d, ws[128 + j], acc);
        }
        if (W < 64)
            acc += chunk_dot_f32((const f32x4*)((const float*)bc2 + (size_t)a * 4096),
                                 lane, s0v, s1v);
    }

    for (int offl = 32; offl > 0; offl >>= 1) acc += __shfl_down(acc, offl);
    if (lane == 0) atomicAdd(&cacc[a * 32], acc);
}

// ---------------- K2b: build fused table (g0,g1,g2,-2w) + b_off' ----------------
__global__ __launch_bounds__(256) void k_prep(
    const void* __restrict__ Wx1, const void* __restrict__ bx1,
    const void* __restrict__ Wx2, const void* __restrict__ bx2,
    const void* __restrict__ eq_param,
    const float* __restrict__ cacc, float* __restrict__ ws)
{
    bool b16 = sniff_bf16(eq_param);
    __shared__ float cv[64];
    __shared__ float red[4];
    int tid = threadIdx.x;
    if (tid < 64) cv[tid] = cacc[tid * 32];
    __syncthreads();
    float w = 0.f;
    for (int a = 0; a < 64; ++a) w = fmaf(ldv(Wx2, tid * 64 + a, b16), cv[a], w);
    float4 t;
    t.x = TWO_LOG2E * ldv(Wx1, tid, b16);         // Wx1[0, j]
    t.y = TWO_LOG2E * ldv(Wx1, HID + tid, b16);   // Wx1[1, j]
    t.z = TWO_LOG2E * ldv(bx1, tid, b16);
    t.w = -2.0f * w;                               // tanh = 1 - 2r; +w folded into b_off
    ((float4*)(ws + 2560))[tid] = t;

    // b_off' = bx2@c + sum_j w_j
    float p = w + ((tid < 64) ? ldv(bx2, tid, b16) * cv[tid] : 0.f);
    for (int offl = 32; offl > 0; offl >>= 1) p += __shfl_down(p, offl);
    if ((tid & 63) == 0) red[tid >> 6] = p;
    __syncthreads();
    if (tid == 0) ws[3584] = red[0] + red[1] + red[2] + red[3];
}

// ---------------- K3: out[n] = b_off' + sum_j (-2 w_j) * rcp(exp2(g)+1) ----------------
// 1024 blocks x 256 threads x 4 pts/thread as two float2 groups (packed f32 ops).
// Paired reciprocal across groups: R = Aa*Ab (pk_mul), r = rcp(R) per half,
// 1/Aa = Ab*r, 1/Ab = Aa*r (pk_mul) -> 6 trans + 15 VALU per 4 elems.
// min(g,30) clamp keeps the pair finite (tanh at g=30 is 1.0f to fp32).
__global__ __launch_bounds__(256) void k_main(
    const void* __restrict__ x, const void* __restrict__ eq_param,
    const float* __restrict__ ws, void* __restrict__ out)
{
    bool b16 = sniff_bf16(eq_param);
    const float4* __restrict__ tbl = (const float4*)(ws + 2560);
    const int stride = NPTS / 4;   // 262144
    int p0 = blockIdx.x * 256 + threadIdx.x;

    float x0[4], x1[4];
    if (b16) {
        #pragma unroll
        for (int i = 0; i < 4; ++i) {
            uint32_t u = ((const uint32_t*)x)[p0 + i * stride];  // packs x[p,0], x[p,1]
            x0[i] = __uint_as_float(u << 16);
            x1[i] = __uint_as_float(u & 0xffff0000u);
        }
    } else {
        #pragma unroll
        for (int i = 0; i < 4; ++i) {
            float2 v = ((const float2*)x)[p0 + i * stride];
            x0[i] = v.x;
            x1[i] = v.y;
        }
    }
    v2f x0a = {x0[0], x0[1]}, x0b = {x0[2], x0[3]};
    v2f x1a = {x1[0], x1[1]}, x1b = {x1[2], x1[3]};

    float boff = ws[3584];
    v2f acca = {boff, boff}, accb = {boff, boff};

    #pragma unroll 4
    for (int jj = 0; jj < HID; ++jj) {
        float4 t = tbl[jj];
        v2f txv = {t.x, t.x}, tyv = {t.y, t.y}, tzv = {t.z, t.z}, twv = {t.w, t.w};
        v2f ga = x0a * txv + x1a * tyv + tzv;   // pk_fma x2
        v2f gb = x0b * txv + x1b * tyv + tzv;
        ga.x = __builtin_fminf(ga.x, 30.0f); ga.y = __builtin_fminf(ga.y, 30.0f);
        gb.x = __builtin_fminf(gb.x, 30.0f); gb.y = __builtin_fminf(gb.y, 30.0f);
        v2f ea, eb;
        ea.x = __builtin_amdgcn_exp2f(ga.x); ea.y = __builtin_amdgcn_exp2f(ga.y);
        eb.x = __builtin_amdgcn_exp2f(gb.x); eb.y = __builtin_amdgcn_exp2f(gb.y);
        v2f onev = {1.0f, 1.0f};
        v2f Aa = ea + onev;                     // pk_add
        v2f Ab = eb + onev;
        v2f R = Aa * Ab;                        // pk_mul
        v2f r;
        r.x = __builtin_amdgcn_rcpf(R.x); r.y = __builtin_amdgcn_rcpf(R.y);
        acca = twv * (Ab * r) + acca;           // pk_mul + pk_fma: += tw * (1/Aa)
        accb = twv * (Aa * r) + accb;           // pk_mul + pk_fma: += tw * (1/Ab)
    }
    float acc[4] = {acca.x, acca.y, accb.x, accb.y};
    if (b16) {
        #pragma unroll
        for (int i = 0; i < 4; ++i)
            ((__hip_bfloat16*)out)[p0 + i * stride] = __float2bfloat16(acc[i]);
    } else {
        #pragma unroll
        for (int i = 0; i < 4; ++i)
            ((float*)out)[p0 + i * stride] = acc[i];
    }
}

extern "C" void kernel_launch(void* const* d_in, const int* in_sizes, int n_in,
                              void* d_out, int out_size, void* d_ws, size_t ws_size,
                              hipStream_t stream) {
    (void)in_sizes; (void)n_in; (void)out_size; (void)ws_size;
    const void* input     = d_in[0];
    const void* eq_param  = d_in[1];
    const void* quad_x0   = d_in[2];
    const void* quad_x1   = d_in[3];
    const void* core_init = d_in[4];
    const void* Wx1  = d_in[5];
    const void* bx1  = d_in[6];
    const void* Wx2  = d_in[7];
    const void* bx2  = d_in[8];
    const void* Wq01 = d_in[9];
    const void* bq01 = d_in[10];
    const void* Wq02 = d_in[11];
    const void* bq02 = d_in[12];
    const void* Wq11 = d_in[13];
    const void* bq11 = d_in[14];
    const void* Wq12 = d_in[15];
    const void* bq12 = d_in[16];
    const void* Wc1  = d_in[17];
    const void* bc1  = d_in[18];
    const void* Wc2  = d_in[19];
    const void* bc2  = d_in[20];

    float* ws = (float*)d_ws;

    // K1: quadrature sums s0,s1 + core hidden t + zero c accumulators
    k_small<<<3, 1024, 0, stream>>>(eq_param, quad_x0, quad_x1,
                                    Wq01, bq01, Wq02, bq02,
                                    Wq11, bq11, Wq12, bq12,
                                    core_init, Wc1, bc1, ws);
    // K2: streaming Tucker-core contraction -> c[64] (4096 waves, 2 chunks each)
    k_core<<<1024, 256, 0, stream>>>(Wc2, bc2, eq_param, ws, ws + 256);
    // K2b: fold c into per-hidden-unit table + b_off
    k_prep<<<1, 256, 0, stream>>>(Wx1, bx1, Wx2, bx2, eq_param, ws + 256, ws);
    // K3: the big fused pointwise MLP + dot (4 pts/thread, packed f32 + paired rcp)
    k_main<<<NPTS / 1024, 256, 0, stream>>>(input, eq_param, ws, d_out);
}